// Round 1
// baseline (634.017 us; speedup 1.0000x reference)
//
#include <hip/hip_runtime.h>

typedef float4 f4;

__device__ __forceinline__ f4 ld4(const float* p) { return *reinterpret_cast<const f4*>(p); }
__device__ __forceinline__ void st4(float* p, f4 v) { *reinterpret_cast<f4*>(p) = v; }

// fake-quant one weight: clip(rint(w/s), -8, 7) * s ; force into SGPR (wave-uniform)
__device__ __forceinline__ float qw(float wv, float s) {
    float r = rintf(wv / s);
    r = fminf(fmaxf(r, -8.f), 7.f);
    float q = r * s;
    return __int_as_float(__builtin_amdgcn_readfirstlane(__float_as_int(q)));
}

// ---------------- identity copy: channels 0..63 of every n ----------------
// per-n: 64 ch * 4096 = 262144 floats at the SAME offset in src and dst.
// 64 n * 65536 f4 = 4,194,304 f4 total.
__global__ __launch_bounds__(256) void ident_k(const float* __restrict__ x,
                                               float* __restrict__ out) {
    int idx = blockIdx.x * 256 + threadIdx.x;   // 4096 blocks -> 1,048,576 threads
#pragma unroll
    for (int t = 0; t < 4; t++) {
        int i = idx + t * 1048576;              // f4 index within the id-section space
        int n = i >> 16;                        // 65536 f4 per n
        int rem = i & 65535;
        int off = n * 262144 + rem;             // f4 units; full n stride = 1048576 floats
        st4(out + (size_t)off * 4, ld4(x + (size_t)off * 4));
    }
}

// ---------------- conv_h: 11x1 vertical, pad (5,5),(0,0), in ch 64..127 ----------------
// block = (n, g, strip of 32 rows). wave -> oc. thread: 8 rows x 4 px.
__global__ __launch_bounds__(256) void conv_h_k(const float* __restrict__ x,
                                                const float* __restrict__ w,
                                                const float* __restrict__ bias,
                                                const float* __restrict__ sp,
                                                float* __restrict__ out) {
    const float s = sp[0];
    int b = blockIdx.x;                 // 64*16*2 = 2048
    int n = b >> 5;
    int g = (b >> 1) & 15;
    int strip = b & 1;
    int wave = threadIdx.x >> 6;
    int lane = threadIdx.x & 63;
    int oc = g * 4 + wave;
    int x0 = (lane & 15) << 2;
    int y0 = strip * 32 + (lane >> 4) * 8;

    float wq[4][11];
#pragma unroll
    for (int ic = 0; ic < 4; ic++)
#pragma unroll
        for (int k = 0; k < 11; k++)
            wq[ic][k] = qw(w[(oc * 4 + ic) * 11 + k], s);

    float bz = bias[oc];
    f4 acc[8];
#pragma unroll
    for (int r = 0; r < 8; r++) { acc[r].x = bz; acc[r].y = bz; acc[r].z = bz; acc[r].w = bz; }

    const float* xin = x + n * 1048576 + (64 + g * 4) * 4096;
#pragma unroll
    for (int ic = 0; ic < 4; ic++) {
        const float* pl = xin + ic * 4096;
        f4 row[18];
#pragma unroll
        for (int j = 0; j < 18; j++) {
            int y = y0 - 5 + j;
            if (y >= 0 && y < 64) row[j] = ld4(pl + y * 64 + x0);
            else { row[j].x = 0.f; row[j].y = 0.f; row[j].z = 0.f; row[j].w = 0.f; }
        }
#pragma unroll
        for (int r = 0; r < 8; r++)
#pragma unroll
            for (int k = 0; k < 11; k++) {
                float wv = wq[ic][k];
                acc[r].x = fmaf(wv, row[r + k].x, acc[r].x);
                acc[r].y = fmaf(wv, row[r + k].y, acc[r].y);
                acc[r].z = fmaf(wv, row[r + k].z, acc[r].z);
                acc[r].w = fmaf(wv, row[r + k].w, acc[r].w);
            }
    }
    float* po = out + n * 1048576 + (64 + oc) * 4096 + y0 * 64 + x0;
#pragma unroll
    for (int r = 0; r < 8; r++) st4(po + r * 64, acc[r]);
}

// ---------------- conv_w: 1x11 horizontal, pad (0,0),(5,5), in ch 128..191 ----------------
// block = (n, g, strip of 16 rows). wave -> oc. thread: 1 row x 16 px.
__global__ __launch_bounds__(256) void conv_w_k(const float* __restrict__ x,
                                                const float* __restrict__ w,
                                                const float* __restrict__ bias,
                                                const float* __restrict__ sp,
                                                float* __restrict__ out) {
    const float s = sp[0];
    int b = blockIdx.x;                 // 64*16*4 = 4096
    int n = b >> 6;
    int g = (b >> 2) & 15;
    int strip = b & 3;
    int wave = threadIdx.x >> 6;
    int lane = threadIdx.x & 63;
    int oc = g * 4 + wave;
    int row = strip * 16 + (lane >> 2);
    int x0 = (lane & 3) << 4;

    float wq[4][11];
#pragma unroll
    for (int ic = 0; ic < 4; ic++)
#pragma unroll
        for (int k = 0; k < 11; k++)
            wq[ic][k] = qw(w[(oc * 4 + ic) * 11 + k], s);

    float bz = bias[oc];
    float acc[16];
#pragma unroll
    for (int p = 0; p < 16; p++) acc[p] = bz;

    const float* xin = x + n * 1048576 + (128 + g * 4) * 4096 + row * 64;
#pragma unroll
    for (int ic = 0; ic < 4; ic++) {
        const float* pl = xin + ic * 4096;
        float buf[32];                  // px x0-8 .. x0+23
#pragma unroll
        for (int t = 0; t < 8; t++) {
            int xb = x0 - 8 + t * 4;
            f4 v;
            if (xb >= 0 && xb < 64) v = ld4(pl + xb);
            else { v.x = 0.f; v.y = 0.f; v.z = 0.f; v.w = 0.f; }
            buf[t * 4 + 0] = v.x; buf[t * 4 + 1] = v.y;
            buf[t * 4 + 2] = v.z; buf[t * 4 + 3] = v.w;
        }
#pragma unroll
        for (int p = 0; p < 16; p++)
#pragma unroll
            for (int k = 0; k < 11; k++)
                acc[p] = fmaf(wq[ic][k], buf[p + 3 + k], acc[p]);
    }
    float* po = out + n * 1048576 + (128 + oc) * 4096 + row * 64 + x0;
#pragma unroll
    for (int t = 0; t < 4; t++) {
        f4 v; v.x = acc[t * 4]; v.y = acc[t * 4 + 1]; v.z = acc[t * 4 + 2]; v.w = acc[t * 4 + 3];
        st4(po + t * 4, v);
    }
}

// ---------------- conv_hw: 3x3, pad (1,1),(1,1), in ch 192..255 ----------------
// block = (n, g, strip of 16 rows). wave -> oc. thread: 2 rows x 8 px.
__global__ __launch_bounds__(256) void conv_hw_k(const float* __restrict__ x,
                                                 const float* __restrict__ w,
                                                 const float* __restrict__ bias,
                                                 const float* __restrict__ sp,
                                                 float* __restrict__ out) {
    const float s = sp[0];
    int b = blockIdx.x;                 // 64*16*4 = 4096
    int n = b >> 6;
    int g = (b >> 2) & 15;
    int strip = b & 3;
    int wave = threadIdx.x >> 6;
    int lane = threadIdx.x & 63;
    int oc = g * 4 + wave;
    int yp = strip * 16 + (lane >> 3) * 2;
    int x0 = (lane & 7) << 3;

    float wq[4][3][3];
#pragma unroll
    for (int ic = 0; ic < 4; ic++)
#pragma unroll
        for (int ky = 0; ky < 3; ky++)
#pragma unroll
            for (int kx = 0; kx < 3; kx++)
                wq[ic][ky][kx] = qw(w[((oc * 4 + ic) * 3 + ky) * 3 + kx], s);

    float bz = bias[oc];
    float acc[2][8];
#pragma unroll
    for (int r = 0; r < 2; r++)
#pragma unroll
        for (int p = 0; p < 8; p++) acc[r][p] = bz;

    const float* xin = x + n * 1048576 + (192 + g * 4) * 4096;
#pragma unroll
    for (int ic = 0; ic < 4; ic++) {
        const float* pl = xin + ic * 4096;
        float buf[4][16];               // rows yp-1..yp+2, px x0-4..x0+11
#pragma unroll
        for (int jr = 0; jr < 4; jr++) {
            int y = yp - 1 + jr;
            bool yok = (y >= 0 && y < 64);
#pragma unroll
            for (int t = 0; t < 4; t++) {
                int xb = x0 - 4 + t * 4;
                f4 v;
                if (yok && xb >= 0 && xb < 64) v = ld4(pl + y * 64 + xb);
                else { v.x = 0.f; v.y = 0.f; v.z = 0.f; v.w = 0.f; }
                buf[jr][t * 4 + 0] = v.x; buf[jr][t * 4 + 1] = v.y;
                buf[jr][t * 4 + 2] = v.z; buf[jr][t * 4 + 3] = v.w;
            }
        }
#pragma unroll
        for (int r = 0; r < 2; r++)
#pragma unroll
            for (int p = 0; p < 8; p++)
#pragma unroll
                for (int ky = 0; ky < 3; ky++)
#pragma unroll
                    for (int kx = 0; kx < 3; kx++)
                        acc[r][p] = fmaf(wq[ic][ky][kx], buf[r + ky][p + 3 + kx], acc[r][p]);
    }
    float* po = out + n * 1048576 + (192 + oc) * 4096 + yp * 64 + x0;
#pragma unroll
    for (int r = 0; r < 2; r++)
#pragma unroll
        for (int t = 0; t < 2; t++) {
            f4 v;
            v.x = acc[r][t * 4]; v.y = acc[r][t * 4 + 1];
            v.z = acc[r][t * 4 + 2]; v.w = acc[r][t * 4 + 3];
            st4(po + r * 64 + t * 4, v);
        }
}

extern "C" void kernel_launch(void* const* d_in, const int* in_sizes, int n_in,
                              void* d_out, int out_size, void* d_ws, size_t ws_size,
                              hipStream_t stream) {
    // setup_inputs order: x, w_hw, b_hw, s_hw, w_w, b_w, s_w, w_h, b_h, s_h
    const float* x    = (const float*)d_in[0];
    const float* w_hw = (const float*)d_in[1];
    const float* b_hw = (const float*)d_in[2];
    const float* s_hw = (const float*)d_in[3];
    const float* w_w  = (const float*)d_in[4];
    const float* b_w  = (const float*)d_in[5];
    const float* s_w  = (const float*)d_in[6];
    const float* w_h  = (const float*)d_in[7];
    const float* b_h  = (const float*)d_in[8];
    const float* s_h  = (const float*)d_in[9];
    float* out = (float*)d_out;

    ident_k<<<4096, 256, 0, stream>>>(x, out);
    conv_h_k<<<2048, 256, 0, stream>>>(x, w_h, b_h, s_h, out);
    conv_w_k<<<4096, 256, 0, stream>>>(x, w_w, b_w, s_w, out);
    conv_hw_k<<<4096, 256, 0, stream>>>(x, w_hw, b_hw, s_hw, out);
}